// Round 1
// baseline (476.091 us; speedup 1.0000x reference)
//
#include <hip/hip_runtime.h>

typedef __attribute__((ext_vector_type(8))) short bf16x8;
typedef __attribute__((ext_vector_type(4))) float f32x4;
typedef __attribute__((ext_vector_type(8))) unsigned short u16x8;

#define USHORT unsigned short

__device__ __forceinline__ USHORT f2bf(float f){
  unsigned int u = __builtin_bit_cast(unsigned int, f);
  u = (u + 0x7FFFu + ((u >> 16) & 1u)) >> 16;
  return (USHORT)u;
}

__device__ __forceinline__ void gl_lds16(const void* g, void* l){
  __builtin_amdgcn_global_load_lds((const __attribute__((address_space(1))) void*)g,
                                   (__attribute__((address_space(3))) void*)l, 16, 0, 0);
}

// ---------------- convert x (fp32 -> bf16), 8 elems/thread ----------------
__global__ __launch_bounds__(256) void cvt_x(const float* __restrict__ x,
                                             USHORT* __restrict__ xb){
  int i = blockIdx.x * 256 + threadIdx.x;      // 1,048,576 threads * 8 = 8,388,608
  const float4* p = (const float4*)x;
  float4 a = p[i*2], b = p[i*2+1];
  u16x8 v;
  v[0]=f2bf(a.x); v[1]=f2bf(a.y); v[2]=f2bf(a.z); v[3]=f2bf(a.w);
  v[4]=f2bf(b.x); v[5]=f2bf(b.y); v[6]=f2bf(b.z); v[7]=f2bf(b.w);
  ((u16x8*)xb)[i] = v;
}

// ------------- transpose + convert fp32 [rows][cols] -> bf16 [cols][rows] -------------
__global__ __launch_bounds__(256) void transpose_f32_bf16(const float* __restrict__ src,
                                                          USHORT* __restrict__ dst,
                                                          int rows, int cols){
  __shared__ USHORT t[32][33];
  int x0 = blockIdx.x * 32, y0 = blockIdx.y * 32;
  int tx = threadIdx.x, ty = threadIdx.y;          // block (32,8)
  #pragma unroll
  for (int i=0;i<4;i++)
    t[ty+i*8][tx] = f2bf(src[(size_t)(y0+ty+i*8)*cols + x0+tx]);
  __syncthreads();
  #pragma unroll
  for (int i=0;i<4;i++)
    dst[(size_t)(x0+ty+i*8)*rows + y0+tx] = t[tx][ty+i*8];
}

// ------------- transpose V [bh][2048][64] bf16 -> VT [bh][64][2048] -------------
__global__ __launch_bounds__(256) void transpose_v(const USHORT* __restrict__ V,
                                                   USHORT* __restrict__ VT){
  __shared__ USHORT t[32][33];
  int bh = blockIdx.z;
  const USHORT* src = V + (size_t)bh*2048*64;
  USHORT* dst = VT + (size_t)bh*64*2048;
  int x0 = blockIdx.x * 32;   // d
  int y0 = blockIdx.y * 32;   // t
  int tx = threadIdx.x, ty = threadIdx.y;
  #pragma unroll
  for (int i=0;i<4;i++)
    t[ty+i*8][tx] = src[(size_t)(y0+ty+i*8)*64 + x0+tx];
  __syncthreads();
  #pragma unroll
  for (int i=0;i<4;i++)
    dst[(size_t)(x0+ty+i*8)*2048 + y0+tx] = t[tx][ty+i*8];
}

// ---------------- m97-style GEMM: C[M,N] = A[M,K] * Bt[N,K]^T ----------------
// EPI 0: write f32 row-major to Cf.  EPI 1: scatter bf16 into Q/K/V [B,H,T,D], Q scaled 1/8.
template<int EPI>
__global__ __launch_bounds__(256) void gemm_bt(
    const USHORT* __restrict__ A, const USHORT* __restrict__ Bt,
    float* __restrict__ Cf,
    USHORT* __restrict__ Qo, USHORT* __restrict__ Ko, USHORT* __restrict__ Vo,
    int M, int N, int K)
{
  __shared__ USHORT As[128*32];
  __shared__ USHORT Bs[128*32];
  const int tid = threadIdx.x;
  const int lane = tid & 63, li = lane & 15, g = lane >> 4;
  const int wv = tid >> 6, wr = wv >> 1, wc = wv & 1;
  const int m0 = blockIdx.y * 128, n0 = blockIdx.x * 128;

  f32x4 acc[4][4];
  #pragma unroll
  for (int m=0;m<4;m++)
    #pragma unroll
    for (int n=0;n<4;n++) acc[m][n] = (f32x4){0.f,0.f,0.f,0.f};

  for (int kk = 0; kk < K; kk += 32){
    __syncthreads();
    #pragma unroll
    for (int it=0; it<2; ++it){
      int c = it*256 + tid;
      int row = c >> 2, sl = c & 3;
      gl_lds16(A  + (size_t)(m0+row)*K + kk + sl*8, &As[c*8]);
      gl_lds16(Bt + (size_t)(n0+row)*K + kk + sl*8, &Bs[c*8]);
    }
    __syncthreads();
    bf16x8 af[4], bfr[4];
    #pragma unroll
    for (int m=0;m<4;m++) af[m]  = *(const bf16x8*)&As[(wr*64+m*16+li)*32 + g*8];
    #pragma unroll
    for (int n=0;n<4;n++) bfr[n] = *(const bf16x8*)&Bs[(wc*64+n*16+li)*32 + g*8];
    #pragma unroll
    for (int m=0;m<4;m++)
      #pragma unroll
      for (int n=0;n<4;n++)
        acc[m][n] = __builtin_amdgcn_mfma_f32_16x16x32_bf16(af[m], bfr[n], acc[m][n], 0,0,0);
  }

  if (EPI == 0){
    #pragma unroll
    for (int m=0;m<4;m++)
      #pragma unroll
      for (int n=0;n<4;n++){
        int col  = n0 + wc*64 + n*16 + li;
        int rowb = m0 + wr*64 + m*16 + g*4;
        #pragma unroll
        for (int r=0;r<4;r++)
          Cf[(size_t)(rowb+r)*N + col] = acc[m][n][r];
      }
  } else {
    #pragma unroll
    for (int m=0;m<4;m++)
      #pragma unroll
      for (int n=0;n<4;n++){
        int col = n0 + wc*64 + n*16 + li;
        int which = col >> 10, hd = col & 1023, h = hd >> 6, d = hd & 63;
        USHORT* dst = (which==0) ? Qo : ((which==1) ? Ko : Vo);
        float sc = (which==0) ? 0.125f : 1.0f;
        int rowb = m0 + wr*64 + m*16 + g*4;
        #pragma unroll
        for (int r=0;r<4;r++){
          int grow = rowb + r;
          int b = grow >> 11, t = grow & 2047;
          dst[((size_t)(b*16+h)*2048 + t)*64 + d] = f2bf(acc[m][n][r]*sc);
        }
      }
  }
}

// ---------------- fused causal attention ----------------
// grid (16 q-tiles, 64 bh). block 256 = 4 waves; wave w owns q rows [q0+32w, q0+32w+32).
// K tile [128][64] bf16 (row = key, XOR swz (row&7)<<4 on 16B slots within 128B rows)
// VT tile [64][128] bf16 (row = d, XOR swz (row&15)<<4 within 256B rows)
// P tile [128][128] bf16 per-wave rows (XOR swz (row&15)<<4 within 256B rows)
__global__ __launch_bounds__(256) void attn_kern(
    const USHORT* __restrict__ Q, const USHORT* __restrict__ Kc,
    const USHORT* __restrict__ VT, USHORT* __restrict__ Aout)
{
  __shared__ USHORT Kl[128*64];
  __shared__ USHORT Vl[64*128];
  __shared__ USHORT Pl[128*128];
  const int qt = blockIdx.x, bh = blockIdx.y;
  const int q0 = qt * 128;
  const int tid = threadIdx.x, lane = tid & 63, li = lane & 15, g = lane >> 4;
  const int wv = tid >> 6;
  const USHORT* Qb = Q  + (size_t)bh*2048*64;
  const USHORT* Kb = Kc + (size_t)bh*2048*64;
  const USHORT* Vb = VT + (size_t)bh*64*2048;

  // Q fragments hoisted to registers (already scaled by 1/8 in GEMM1 epilogue)
  bf16x8 aq[2][2];
  #pragma unroll
  for (int m=0;m<2;m++)
    #pragma unroll
    for (int ks=0;ks<2;ks++){
      int row = q0 + wv*32 + m*16 + li;
      aq[m][ks] = *(const bf16x8*)&Qb[(size_t)row*64 + ks*32 + g*8];
    }

  f32x4 o[2][4];
  float mrun[2][4], lrun[2][4];
  #pragma unroll
  for (int m=0;m<2;m++){
    #pragma unroll
    for (int n=0;n<4;n++) o[m][n] = (f32x4){0.f,0.f,0.f,0.f};
    #pragma unroll
    for (int r=0;r<4;r++){ mrun[m][r] = -1e30f; lrun[m][r] = 0.f; }
  }

  const int nkt = qt + 1;
  for (int kt = 0; kt < nkt; ++kt){
    __syncthreads();
    // stage K [128][64] and VT [64][128] with inverse-swizzled global source
    #pragma unroll
    for (int it=0; it<4; ++it){
      int c = it*256 + tid;
      { int row = c >> 3, sl = c & 7, gs = sl ^ (row & 7);
        gl_lds16(Kb + ((size_t)(kt*128+row))*64 + gs*8, &Kl[c*8]); }
      { int row = c >> 4, sl = c & 15, gs = sl ^ (row & 15);
        gl_lds16(Vb + (size_t)row*2048 + kt*128 + gs*8, &Vl[c*8]); }
    }
    __syncthreads();

    // S = Q K^T  (swizzled ds_read of K)
    f32x4 s[2][8];
    #pragma unroll
    for (int m=0;m<2;m++)
      #pragma unroll
      for (int nf=0;nf<8;nf++){
        f32x4 z = (f32x4){0.f,0.f,0.f,0.f};
        #pragma unroll
        for (int ks=0;ks<2;ks++){
          int key = nf*16 + li;
          int addr = (key*128 + ks*64 + g*16) ^ ((key & 7) << 4);
          bf16x8 bk = *(const bf16x8*)((const char*)Kl + addr);
          z = __builtin_amdgcn_mfma_f32_16x16x32_bf16(aq[m][ks], bk, z, 0,0,0);
        }
        s[m][nf] = z;
      }

    // causal mask on diagonal tile
    if (kt == qt){
      #pragma unroll
      for (int m=0;m<2;m++){
        int rowb = q0 + wv*32 + m*16 + g*4;
        #pragma unroll
        for (int nf=0;nf<8;nf++){
          int col = kt*128 + nf*16 + li;
          #pragma unroll
          for (int r=0;r<4;r++)
            if (col > rowb + r) s[m][nf][r] = -1e30f;
        }
      }
    }

    // online softmax + write P to per-wave LDS region (swizzled)
    #pragma unroll
    for (int m=0;m<2;m++){
      #pragma unroll
      for (int r=0;r<4;r++){
        float v = s[m][0][r];
        #pragma unroll
        for (int nf=1;nf<8;nf++) v = fmaxf(v, s[m][nf][r]);
        #pragma unroll
        for (int d=1;d<16;d<<=1) v = fmaxf(v, __shfl_xor(v, d, 64));
        float mnew = fmaxf(mrun[m][r], v);
        float scale = __expf(mrun[m][r] - mnew);
        float psum = 0.f;
        #pragma unroll
        for (int nf=0;nf<8;nf++){
          float p = __expf(s[m][nf][r] - mnew);
          s[m][nf][r] = p;
          psum += p;
        }
        #pragma unroll
        for (int d=1;d<16;d<<=1) psum += __shfl_xor(psum, d, 64);
        lrun[m][r] = lrun[m][r]*scale + psum;
        mrun[m][r] = mnew;
        #pragma unroll
        for (int nd=0;nd<4;nd++) o[m][nd][r] *= scale;
      }
      #pragma unroll
      for (int nf=0;nf<8;nf++)
        #pragma unroll
        for (int r=0;r<4;r++){
          int prow = wv*32 + m*16 + g*4 + r;
          int pcol = nf*16 + li;
          int addr = (prow*256 + pcol*2) ^ ((prow & 15) << 4);
          *(USHORT*)((char*)Pl + addr) = f2bf(s[m][nf][r]);
        }
    }
    __syncthreads();

    // O += P V  (A-layout read of P, swizzled; B from VT, swizzled)
    #pragma unroll
    for (int m=0;m<2;m++)
      #pragma unroll
      for (int nd=0;nd<4;nd++){
        #pragma unroll
        for (int ks=0;ks<4;ks++){
          int prow = wv*32 + m*16 + li;
          int paddr = (prow*256 + ks*64 + g*16) ^ ((prow & 15) << 4);
          bf16x8 pa = *(const bf16x8*)((const char*)Pl + paddr);
          int d = nd*16 + li;
          int vaddr = (d*256 + ks*64 + g*16) ^ ((d & 15) << 4);
          bf16x8 vb = *(const bf16x8*)((const char*)Vl + vaddr);
          o[m][nd] = __builtin_amdgcn_mfma_f32_16x16x32_bf16(pa, vb, o[m][nd], 0,0,0);
        }
      }
  }

  // epilogue: O / l -> Aout [B,T,C] bf16
  const int b = bh >> 4, h = bh & 15;
  #pragma unroll
  for (int m=0;m<2;m++)
    #pragma unroll
    for (int nd=0;nd<4;nd++)
      #pragma unroll
      for (int r=0;r<4;r++){
        int t = q0 + wv*32 + m*16 + g*4 + r;
        int d = nd*16 + li;
        float val = o[m][nd][r] / lrun[m][r];
        Aout[((size_t)(b*2048 + t))*1024 + h*64 + d] = f2bf(val);
      }
}

// ---------------- launch ----------------
extern "C" void kernel_launch(void* const* d_in, const int* in_sizes, int n_in,
                              void* d_out, int out_size, void* d_ws, size_t ws_size,
                              hipStream_t stream) {
  const float* x     = (const float*)d_in[0];
  const float* w_qkv = (const float*)d_in[1];
  const float* w_out = (const float*)d_in[2];
  float* out = (float*)d_out;
  char* ws = (char*)d_ws;

  USHORT* xb    = (USHORT*)(ws);               // 16,777,216 B  (reused as VT)
  USHORT* wqkvT = (USHORT*)(ws + 16777216);    //  6,291,456 B
  USHORT* woutT = (USHORT*)(ws + 23068672);    //  2,097,152 B
  USHORT* Qb    = (USHORT*)(ws + 25165824);    // 16,777,216 B
  USHORT* Kb    = (USHORT*)(ws + 41943040);    // 16,777,216 B
  USHORT* Vb    = (USHORT*)(ws + 58720256);    // 16,777,216 B (reused as Aout)
  USHORT* VT    = xb;     // x dead after GEMM1
  USHORT* Aout  = Vb;     // V dead after transpose_v

  cvt_x<<<4096, 256, 0, stream>>>(x, xb);
  transpose_f32_bf16<<<dim3(96,32), dim3(32,8), 0, stream>>>(w_qkv, wqkvT, 1024, 3072);
  transpose_f32_bf16<<<dim3(32,32), dim3(32,8), 0, stream>>>(w_out, woutT, 1024, 1024);
  gemm_bt<1><<<dim3(24,64), 256, 0, stream>>>(xb, wqkvT, nullptr, Qb, Kb, Vb, 8192, 3072, 1024);
  transpose_v<<<dim3(2,64,64), dim3(32,8), 0, stream>>>(Vb, VT);
  attn_kern<<<dim3(16,64), 256, 0, stream>>>(Qb, Kb, VT, Aout);
  gemm_bt<0><<<dim3(8,64), 256, 0, stream>>>(Aout, woutT, out, nullptr, nullptr, nullptr, 8192, 1024, 1024);
}

// Round 2
// 448.821 us; speedup vs baseline: 1.0608x; 1.0608x over previous
//
#include <hip/hip_runtime.h>

typedef __attribute__((ext_vector_type(8))) short bf16x8;
typedef __attribute__((ext_vector_type(4))) float f32x4;
typedef __attribute__((ext_vector_type(8))) unsigned short u16x8;

#define USHORT unsigned short

__device__ __forceinline__ USHORT f2bf(float f){
  unsigned int u = __builtin_bit_cast(unsigned int, f);
  u = (u + 0x7FFFu + ((u >> 16) & 1u)) >> 16;
  return (USHORT)u;
}

__device__ __forceinline__ void gl_lds16(const void* g, void* l){
  __builtin_amdgcn_global_load_lds((const __attribute__((address_space(1))) void*)g,
                                   (__attribute__((address_space(3))) void*)l, 16, 0, 0);
}

// ---------------- convert x (fp32 -> bf16), 8 elems/thread ----------------
__global__ __launch_bounds__(256) void cvt_x(const float* __restrict__ x,
                                             USHORT* __restrict__ xb){
  int i = blockIdx.x * 256 + threadIdx.x;
  const float4* p = (const float4*)x;
  float4 a = p[i*2], b = p[i*2+1];
  u16x8 v;
  v[0]=f2bf(a.x); v[1]=f2bf(a.y); v[2]=f2bf(a.z); v[3]=f2bf(a.w);
  v[4]=f2bf(b.x); v[5]=f2bf(b.y); v[6]=f2bf(b.z); v[7]=f2bf(b.w);
  ((u16x8*)xb)[i] = v;
}

// ------------- transpose + convert fp32 [rows][cols] -> bf16 [cols][rows] -------------
__global__ __launch_bounds__(256) void transpose_f32_bf16(const float* __restrict__ src,
                                                          USHORT* __restrict__ dst,
                                                          int rows, int cols){
  __shared__ USHORT t[32][33];
  int x0 = blockIdx.x * 32, y0 = blockIdx.y * 32;
  int tx = threadIdx.x, ty = threadIdx.y;
  #pragma unroll
  for (int i=0;i<4;i++)
    t[ty+i*8][tx] = f2bf(src[(size_t)(y0+ty+i*8)*cols + x0+tx]);
  __syncthreads();
  #pragma unroll
  for (int i=0;i<4;i++)
    dst[(size_t)(x0+ty+i*8)*rows + y0+tx] = t[tx][ty+i*8];
}

// ------------- transpose V [bh][2048][64] bf16 -> VT [bh][64][2048] -------------
__global__ __launch_bounds__(256) void transpose_v(const USHORT* __restrict__ V,
                                                   USHORT* __restrict__ VT){
  __shared__ USHORT t[32][33];
  int bh = blockIdx.z;
  const USHORT* src = V + (size_t)bh*2048*64;
  USHORT* dst = VT + (size_t)bh*64*2048;
  int x0 = blockIdx.x * 32;   // d
  int y0 = blockIdx.y * 32;   // t
  int tx = threadIdx.x, ty = threadIdx.y;
  #pragma unroll
  for (int i=0;i<4;i++)
    t[ty+i*8][tx] = src[(size_t)(y0+ty+i*8)*64 + x0+tx];
  __syncthreads();
  #pragma unroll
  for (int i=0;i<4;i++)
    dst[(size_t)(x0+ty+i*8)*2048 + y0+tx] = t[tx][ty+i*8];
}

// ---------------- m97-style GEMM: C[M,N] = A[M,K] * Bt[N,K]^T ----------------
template<int EPI>
__global__ __launch_bounds__(256) void gemm_bt(
    const USHORT* __restrict__ A, const USHORT* __restrict__ Bt,
    float* __restrict__ Cf,
    USHORT* __restrict__ Qo, USHORT* __restrict__ Ko, USHORT* __restrict__ Vo,
    int M, int N, int K)
{
  __shared__ USHORT As[128*32];
  __shared__ USHORT Bs[128*32];
  const int tid = threadIdx.x;
  const int lane = tid & 63, li = lane & 15, g = lane >> 4;
  const int wv = tid >> 6, wr = wv >> 1, wc = wv & 1;
  const int m0 = blockIdx.y * 128, n0 = blockIdx.x * 128;

  f32x4 acc[4][4];
  #pragma unroll
  for (int m=0;m<4;m++)
    #pragma unroll
    for (int n=0;n<4;n++) acc[m][n] = (f32x4){0.f,0.f,0.f,0.f};

  for (int kk = 0; kk < K; kk += 32){
    __syncthreads();
    #pragma unroll
    for (int it=0; it<2; ++it){
      int c = it*256 + tid;
      int row = c >> 2, sl = c & 3;
      gl_lds16(A  + (size_t)(m0+row)*K + kk + sl*8, &As[c*8]);
      gl_lds16(Bt + (size_t)(n0+row)*K + kk + sl*8, &Bs[c*8]);
    }
    __syncthreads();
    bf16x8 af[4], bfr[4];
    #pragma unroll
    for (int m=0;m<4;m++) af[m]  = *(const bf16x8*)&As[(wr*64+m*16+li)*32 + g*8];
    #pragma unroll
    for (int n=0;n<4;n++) bfr[n] = *(const bf16x8*)&Bs[(wc*64+n*16+li)*32 + g*8];
    #pragma unroll
    for (int m=0;m<4;m++)
      #pragma unroll
      for (int n=0;n<4;n++)
        acc[m][n] = __builtin_amdgcn_mfma_f32_16x16x32_bf16(af[m], bfr[n], acc[m][n], 0,0,0);
  }

  if (EPI == 0){
    #pragma unroll
    for (int m=0;m<4;m++)
      #pragma unroll
      for (int n=0;n<4;n++){
        int col  = n0 + wc*64 + n*16 + li;
        int rowb = m0 + wr*64 + m*16 + g*4;
        #pragma unroll
        for (int r=0;r<4;r++)
          Cf[(size_t)(rowb+r)*N + col] = acc[m][n][r];
      }
  } else {
    #pragma unroll
    for (int m=0;m<4;m++)
      #pragma unroll
      for (int n=0;n<4;n++){
        int col = n0 + wc*64 + n*16 + li;
        int which = col >> 10, hd = col & 1023, h = hd >> 6, d = hd & 63;
        USHORT* dst = (which==0) ? Qo : ((which==1) ? Ko : Vo);
        float sc = (which==0) ? 0.125f : 1.0f;
        int rowb = m0 + wr*64 + m*16 + g*4;
        #pragma unroll
        for (int r=0;r<4;r++){
          int grow = rowb + r;
          int b = grow >> 11, t = grow & 2047;
          dst[((size_t)(b*16+h)*2048 + t)*64 + d] = f2bf(acc[m][n][r]*sc);
        }
      }
  }
}

// ---------------- fused causal attention (barrier-free) ----------------
// grid (16 q-tiles, 64 bh), block 256 = 4 waves; wave w owns q rows [q0+32w, q0+32w+32).
// KVBLK = 64. K and V^T fragments are loaded DIRECTLY from global (L2-resident,
// 512 KB/bh) -- no K/V LDS staging, no __syncthreads anywhere.
// P goes through a per-wave 4 KB LDS region (XOR-swizzled), guarded only by
// an in-wave s_waitcnt lgkmcnt(0).
__global__ __launch_bounds__(256) void attn_kern(
    const USHORT* __restrict__ Q, const USHORT* __restrict__ Kc,
    const USHORT* __restrict__ VT, USHORT* __restrict__ Aout)
{
  __shared__ USHORT Pl[4][32*64];          // per-wave [32 q][64 k] bf16, swizzled
  const int qt = 15 - blockIdx.x;          // heavy tiles dispatch first
  const int bh = blockIdx.y;
  const int q0 = qt * 128;
  const int tid = threadIdx.x, lane = tid & 63, li = lane & 15, g = lane >> 4;
  const int wv = tid >> 6;
  const USHORT* Qb = Q  + (size_t)bh*2048*64;
  const USHORT* Kb = Kc + (size_t)bh*2048*64;
  const USHORT* Vb = VT + (size_t)bh*64*2048;
  char* pw = (char*)&Pl[wv][0];

  // Q fragments in registers (pre-scaled by 1/8 in GEMM1 epilogue)
  bf16x8 aq[2][2];
  #pragma unroll
  for (int m=0;m<2;m++)
    #pragma unroll
    for (int ks=0;ks<2;ks++){
      int row = q0 + wv*32 + m*16 + li;
      aq[m][ks] = *(const bf16x8*)&Qb[(size_t)row*64 + ks*32 + g*8];
    }

  f32x4 o[2][4];
  float mrun[2][4], lrun[2][4];
  #pragma unroll
  for (int m=0;m<2;m++){
    #pragma unroll
    for (int n=0;n<4;n++) o[m][n] = (f32x4){0.f,0.f,0.f,0.f};
    #pragma unroll
    for (int r=0;r<4;r++){ mrun[m][r] = -1e30f; lrun[m][r] = 0.f; }
  }

  const int nkt = 2*qt + 2;                // 64-key tiles, causal
  for (int kt = 0; kt < nkt; ++kt){
    const USHORT* Kt = Kb + (size_t)kt*64*64;

    // ---- S = Q K^T : B-fragments straight from global K (row=key, 16B contig)
    f32x4 s[2][4];
    #pragma unroll
    for (int m=0;m<2;m++)
      #pragma unroll
      for (int nf=0;nf<4;nf++){
        f32x4 z = (f32x4){0.f,0.f,0.f,0.f};
        #pragma unroll
        for (int ks=0;ks<2;ks++){
          bf16x8 bk = *(const bf16x8*)&Kt[(size_t)(nf*16+li)*64 + ks*32 + g*8];
          z = __builtin_amdgcn_mfma_f32_16x16x32_bf16(aq[m][ks], bk, z, 0,0,0);
        }
        s[m][nf] = z;
      }

    // ---- causal mask (only the last two tiles can violate)
    if (kt >= 2*qt){
      #pragma unroll
      for (int m=0;m<2;m++){
        int rowb = q0 + wv*32 + m*16 + g*4;
        #pragma unroll
        for (int nf=0;nf<4;nf++){
          int col = kt*64 + nf*16 + li;
          #pragma unroll
          for (int r=0;r<4;r++)
            if (col > rowb + r) s[m][nf][r] = -1e30f;
        }
      }
    }

    // ---- online softmax (row = q lives on 16 lanes li, 4 frags nf)
    #pragma unroll
    for (int m=0;m<2;m++){
      #pragma unroll
      for (int r=0;r<4;r++){
        float v = s[m][0][r];
        #pragma unroll
        for (int nf=1;nf<4;nf++) v = fmaxf(v, s[m][nf][r]);
        #pragma unroll
        for (int d=1;d<16;d<<=1) v = fmaxf(v, __shfl_xor(v, d, 64));
        float mnew = fmaxf(mrun[m][r], v);
        float scale = __expf(mrun[m][r] - mnew);
        float psum = 0.f;
        #pragma unroll
        for (int nf=0;nf<4;nf++){
          float p = __expf(s[m][nf][r] - mnew);
          s[m][nf][r] = p;
          psum += p;
        }
        #pragma unroll
        for (int d=1;d<16;d<<=1) psum += __shfl_xor(psum, d, 64);
        lrun[m][r] = lrun[m][r]*scale + psum;
        mrun[m][r] = mnew;
        #pragma unroll
        for (int nd=0;nd<4;nd++) o[m][nd][r] *= scale;
      }
      // P write to own wave's LDS region, XOR-swizzled rows of 128 B
      #pragma unroll
      for (int nf=0;nf<4;nf++)
        #pragma unroll
        for (int r=0;r<4;r++){
          int q = m*16 + g*4 + r;
          int key = nf*16 + li;
          int addr = q*128 + ((key*2) ^ ((q & 7) << 4));
          *(USHORT*)(pw + addr) = f2bf(s[m][nf][r]);
        }
    }

    // in-wave producer->consumer: drain ds_writes before ds_reads (no barrier)
    asm volatile("s_waitcnt lgkmcnt(0)" ::: "memory");
    __builtin_amdgcn_sched_barrier(0);

    // ---- O += P V : A from swizzled LDS P, B straight from global VT
    #pragma unroll
    for (int m=0;m<2;m++){
      int prow = m*16 + li;
      int xorv = (prow & 7) << 4;
      #pragma unroll
      for (int ks=0;ks<2;ks++){
        bf16x8 pa = *(const bf16x8*)(pw + prow*128 + ((ks*64 + g*16) ^ xorv));
        #pragma unroll
        for (int nd=0;nd<4;nd++){
          bf16x8 vb = *(const bf16x8*)&Vb[(size_t)(nd*16+li)*2048 + kt*64 + ks*32 + g*8];
          o[m][nd] = __builtin_amdgcn_mfma_f32_16x16x32_bf16(pa, vb, o[m][nd], 0,0,0);
        }
      }
    }
  }

  // ---- epilogue: O / l -> Aout [B,T,C] bf16
  const int b = bh >> 4, h = bh & 15;
  #pragma unroll
  for (int m=0;m<2;m++)
    #pragma unroll
    for (int nd=0;nd<4;nd++)
      #pragma unroll
      for (int r=0;r<4;r++){
        int t = q0 + wv*32 + m*16 + g*4 + r;
        int d = nd*16 + li;
        float val = o[m][nd][r] / lrun[m][r];
        Aout[((size_t)(b*2048 + t))*1024 + h*64 + d] = f2bf(val);
      }
}

// ---------------- launch ----------------
extern "C" void kernel_launch(void* const* d_in, const int* in_sizes, int n_in,
                              void* d_out, int out_size, void* d_ws, size_t ws_size,
                              hipStream_t stream) {
  const float* x     = (const float*)d_in[0];
  const float* w_qkv = (const float*)d_in[1];
  const float* w_out = (const float*)d_in[2];
  float* out = (float*)d_out;
  char* ws = (char*)d_ws;

  USHORT* xb    = (USHORT*)(ws);               // 16,777,216 B  (reused as VT)
  USHORT* wqkvT = (USHORT*)(ws + 16777216);    //  6,291,456 B
  USHORT* woutT = (USHORT*)(ws + 23068672);    //  2,097,152 B
  USHORT* Qb    = (USHORT*)(ws + 25165824);    // 16,777,216 B
  USHORT* Kb    = (USHORT*)(ws + 41943040);    // 16,777,216 B
  USHORT* Vb    = (USHORT*)(ws + 58720256);    // 16,777,216 B (reused as Aout)
  USHORT* VT    = xb;     // x dead after GEMM1
  USHORT* Aout  = Vb;     // V dead after transpose_v

  cvt_x<<<4096, 256, 0, stream>>>(x, xb);
  transpose_f32_bf16<<<dim3(96,32), dim3(32,8), 0, stream>>>(w_qkv, wqkvT, 1024, 3072);
  transpose_f32_bf16<<<dim3(32,32), dim3(32,8), 0, stream>>>(w_out, woutT, 1024, 1024);
  gemm_bt<1><<<dim3(24,64), 256, 0, stream>>>(xb, wqkvT, nullptr, Qb, Kb, Vb, 8192, 3072, 1024);
  transpose_v<<<dim3(2,64,64), dim3(32,8), 0, stream>>>(Vb, VT);
  attn_kern<<<dim3(16,64), 256, 0, stream>>>(Qb, Kb, VT, Aout);
  gemm_bt<0><<<dim3(8,64), 256, 0, stream>>>(Aout, woutT, out, nullptr, nullptr, nullptr, 8192, 1024, 1024);
}

// Round 12
// 429.959 us; speedup vs baseline: 1.1073x; 1.0439x over previous
//
#include <hip/hip_runtime.h>

typedef __attribute__((ext_vector_type(8))) short bf16x8;
typedef __attribute__((ext_vector_type(4))) float f32x4;
typedef __attribute__((ext_vector_type(16))) float f32x16;
typedef __attribute__((ext_vector_type(8))) unsigned short u16x8;
typedef __attribute__((ext_vector_type(2))) int i32x2;

#define USHORT unsigned short

__device__ __forceinline__ USHORT f2bf(float f){
  unsigned int u = __builtin_bit_cast(unsigned int, f);
  u = (u + 0x7FFFu + ((u >> 16) & 1u)) >> 16;
  return (USHORT)u;
}

__device__ __forceinline__ void gl_lds16(const void* g, void* l){
  __builtin_amdgcn_global_load_lds((const __attribute__((address_space(1))) void*)g,
                                   (__attribute__((address_space(3))) void*)l, 16, 0, 0);
}

// v_cvt_pk_bf16_f32: lo -> [15:0], hi -> [31:16], RNE
__device__ __forceinline__ int cvtpk(float lo, float hi){
  int r;
  asm("v_cvt_pk_bf16_f32 %0, %1, %2" : "=v"(r) : "v"(lo), "v"(hi));
  return r;
}

__device__ __forceinline__ float sx32f(float v){ return __shfl_xor(v, 32, 64); }

// ---------------- convert x (fp32 -> bf16), 8 elems/thread ----------------
__global__ __launch_bounds__(256) void cvt_x(const float* __restrict__ x,
                                             USHORT* __restrict__ xb){
  int i = blockIdx.x * 256 + threadIdx.x;
  const float4* p = (const float4*)x;
  float4 a = p[i*2], b = p[i*2+1];
  u16x8 v;
  v[0]=f2bf(a.x); v[1]=f2bf(a.y); v[2]=f2bf(a.z); v[3]=f2bf(a.w);
  v[4]=f2bf(b.x); v[5]=f2bf(b.y); v[6]=f2bf(b.z); v[7]=f2bf(b.w);
  ((u16x8*)xb)[i] = v;
}

// ------------- transpose + convert fp32 [rows][cols] -> bf16 [cols][rows] -------------
__global__ __launch_bounds__(256) void transpose_f32_bf16(const float* __restrict__ src,
                                                          USHORT* __restrict__ dst,
                                                          int rows, int cols){
  __shared__ USHORT t[32][33];
  int x0 = blockIdx.x * 32, y0 = blockIdx.y * 32;
  int tx = threadIdx.x, ty = threadIdx.y;
  #pragma unroll
  for (int i=0;i<4;i++)
    t[ty+i*8][tx] = f2bf(src[(size_t)(y0+ty+i*8)*cols + x0+tx]);
  __syncthreads();
  #pragma unroll
  for (int i=0;i<4;i++)
    dst[(size_t)(x0+ty+i*8)*rows + y0+tx] = t[tx][ty+i*8];
}

// ------------- transpose V [bh][2048][64] bf16 -> VT [bh][64][2048] -------------
__global__ __launch_bounds__(256) void transpose_v(const USHORT* __restrict__ V,
                                                   USHORT* __restrict__ VT){
  __shared__ USHORT t[32][33];
  int bh = blockIdx.z;
  const USHORT* src = V + (size_t)bh*2048*64;
  USHORT* dst = VT + (size_t)bh*64*2048;
  int x0 = blockIdx.x * 32;   // d
  int y0 = blockIdx.y * 32;   // t
  int tx = threadIdx.x, ty = threadIdx.y;
  #pragma unroll
  for (int i=0;i<4;i++)
    t[ty+i*8][tx] = src[(size_t)(y0+ty+i*8)*64 + x0+tx];
  __syncthreads();
  #pragma unroll
  for (int i=0;i<4;i++)
    dst[(size_t)(x0+ty+i*8)*2048 + y0+tx] = t[tx][ty+i*8];
}

// ---------------- m97-style GEMM: C[M,N] = A[M,K] * Bt[N,K]^T ----------------
template<int EPI>
__global__ __launch_bounds__(256) void gemm_bt(
    const USHORT* __restrict__ A, const USHORT* __restrict__ Bt,
    float* __restrict__ Cf,
    USHORT* __restrict__ Qo, USHORT* __restrict__ Ko, USHORT* __restrict__ Vo,
    int M, int N, int K)
{
  __shared__ USHORT As[128*32];
  __shared__ USHORT Bs[128*32];
  const int tid = threadIdx.x;
  const int lane = tid & 63, li = lane & 15, g = lane >> 4;
  const int wv = tid >> 6, wr = wv >> 1, wc = wv & 1;
  const int m0 = blockIdx.y * 128, n0 = blockIdx.x * 128;

  f32x4 acc[4][4];
  #pragma unroll
  for (int m=0;m<4;m++)
    #pragma unroll
    for (int n=0;n<4;n++) acc[m][n] = (f32x4){0.f,0.f,0.f,0.f};

  for (int kk = 0; kk < K; kk += 32){
    __syncthreads();
    #pragma unroll
    for (int it=0; it<2; ++it){
      int c = it*256 + tid;
      int row = c >> 2, sl = c & 3;
      gl_lds16(A  + (size_t)(m0+row)*K + kk + sl*8, &As[c*8]);
      gl_lds16(Bt + (size_t)(n0+row)*K + kk + sl*8, &Bs[c*8]);
    }
    __syncthreads();
    bf16x8 af[4], bfr[4];
    #pragma unroll
    for (int m=0;m<4;m++) af[m]  = *(const bf16x8*)&As[(wr*64+m*16+li)*32 + g*8];
    #pragma unroll
    for (int n=0;n<4;n++) bfr[n] = *(const bf16x8*)&Bs[(wc*64+n*16+li)*32 + g*8];
    #pragma unroll
    for (int m=0;m<4;m++)
      #pragma unroll
      for (int n=0;n<4;n++)
        acc[m][n] = __builtin_amdgcn_mfma_f32_16x16x32_bf16(af[m], bfr[n], acc[m][n], 0,0,0);
  }

  if (EPI == 0){
    #pragma unroll
    for (int m=0;m<4;m++)
      #pragma unroll
      for (int n=0;n<4;n++){
        int col  = n0 + wc*64 + n*16 + li;
        int rowb = m0 + wr*64 + m*16 + g*4;
        #pragma unroll
        for (int r=0;r<4;r++)
          Cf[(size_t)(rowb+r)*N + col] = acc[m][n][r];
      }
  } else {
    #pragma unroll
    for (int m=0;m<4;m++)
      #pragma unroll
      for (int n=0;n<4;n++){
        int col = n0 + wc*64 + n*16 + li;
        int which = col >> 10, hd = col & 1023, h = hd >> 6, d = hd & 63;
        USHORT* dst = (which==0) ? Qo : ((which==1) ? Ko : Vo);
        // Q pre-scale: 1/sqrt(64) * log2(e)  (softmax uses exp2)
        float sc = (which==0) ? 0.18033688f : 1.0f;
        int rowb = m0 + wr*64 + m*16 + g*4;
        #pragma unroll
        for (int r=0;r<4;r++){
          int grow = rowb + r;
          int b = grow >> 11, t = grow & 2047;
          dst[((size_t)(b*16+h)*2048 + t)*64 + d] = f2bf(acc[m][n][r]*sc);
        }
      }
  }
}

// ---------------- fused causal attention: register softmax, P via per-wave LDS ----------------
// grid (16,64), 4 waves/block; wave wv owns q rows [qt*128+wv*32, +32).
// Swapped QK^T via mfma_32x32x16: S^T[key,q]; lane holds col q=lane&31,
// 16 keys (rows) across regs: key = (r&3)+8*(r>>2)+4*(lane>>5)  [C/D layout, m74/m101].
// Softmax in-register (in-lane trees + shfl_xor(32) reduce). P goes to a per-wave
// 2KB LDS tile P[q=l31][key] (XOR-swizzled rows), then read back as contiguous
// ds_read_b128 B-fragments for PV. Placement-robust: correctness relies only on
// f_A == f_B (operand k-maps equal), not on their specific form.
__global__ __launch_bounds__(256) void attn_kern(
    const USHORT* __restrict__ Q, const USHORT* __restrict__ Kc,
    const USHORT* __restrict__ VT, USHORT* __restrict__ Aout)
{
  __shared__ USHORT Pl[4][32*32];          // per-wave [32 q][32 key] bf16, 64B rows
  const int qt = 15 - blockIdx.x;          // heavy tiles dispatch first
  const int bh = blockIdx.y;
  const int tid = threadIdx.x;
  const int lane = tid & 63, l31 = lane & 31;
  const int hi = lane >> 5;
  const int wv = tid >> 6;
  const int qbase = qt*128 + wv*32;
  const int nkt = 4*qt + wv + 1;           // 32-key tiles, causal
  char* pw = (char*)&Pl[wv][0];
  const int swz = ((l31 >> 1) & 3) << 4;   // row-dependent 16B-slot XOR swizzle

  const USHORT* Qb = Q  + (size_t)bh*2048*64;
  const USHORT* Kb = Kc + (size_t)bh*2048*64;
  const USHORT* Vb = VT + (size_t)bh*64*2048;

  const USHORT* Qlane = Qb + (size_t)(qbase + l31)*64 + hi*8;
  const USHORT* Klane = Kb + (size_t)l31*64 + hi*8;     // + kt*2048 + ks*16
  const USHORT* Vlane = Vb + (size_t)l31*2048 + hi*8;   // + 32*2048 (o1), + kt*32 + ks*16

  bf16x8 qf[4];
  #pragma unroll
  for (int ks=0;ks<4;ks++) qf[ks] = *(const bf16x8*)(Qlane + ks*16);

  f32x16 o0 = {}, o1 = {};
  float mrun = -1e30f, lrun = 0.f;

  bf16x8 kf[4];
  #pragma unroll
  for (int ks=0;ks<4;ks++) kf[ks] = *(const bf16x8*)(Klane + ks*16);

  for (int kt = 0; kt < nkt; ++kt){
    // V fragments for this tile (in flight across QK + softmax)
    bf16x8 vf0[2], vf1[2];
    #pragma unroll
    for (int ks=0;ks<2;ks++){
      vf0[ks] = *(const bf16x8*)(Vlane + kt*32 + ks*16);
      vf1[ks] = *(const bf16x8*)(Vlane + 32*2048 + kt*32 + ks*16);
    }

    // S^T = K * Q^T over D=64 (4 k-steps)
    f32x16 s = {};
    #pragma unroll
    for (int ks=0;ks<4;ks++)
      s = __builtin_amdgcn_mfma_f32_32x32x16_bf16(kf[ks], qf[ks], s, 0,0,0);

    // prefetch next K tile
    int ktp = (kt+1 < nkt) ? kt+1 : kt;
    bf16x8 kn[4];
    #pragma unroll
    for (int ks=0;ks<4;ks++)
      kn[ks] = *(const bf16x8*)(Klane + (size_t)ktp*2048 + ks*16);

    // causal mask (last tile only): key_global > q_global -> -inf
    if (kt == nkt-1){
      #pragma unroll
      for (int r=0;r<16;r++){
        int key = kt*32 + (r&3) + 8*(r>>2) + 4*hi;
        if (key > qbase + l31) s[r] = -1e30f;
      }
    }

    // ---- softmax: in-lane tree + one cross-half exchange
    float a0 = fmaxf(s[0],s[1]),  a1 = fmaxf(s[2],s[3]),  a2 = fmaxf(s[4],s[5]),  a3 = fmaxf(s[6],s[7]);
    float a4 = fmaxf(s[8],s[9]),  a5 = fmaxf(s[10],s[11]),a6 = fmaxf(s[12],s[13]),a7 = fmaxf(s[14],s[15]);
    float b0 = fmaxf(a0,a1), b1 = fmaxf(a2,a3), b2 = fmaxf(a4,a5), b3 = fmaxf(a6,a7);
    float vmax = fmaxf(fmaxf(b0,b1), fmaxf(b2,b3));
    float pmax = fmaxf(vmax, sx32f(vmax));

    // defer-max (T13): skip O-rescale while max growth <= 8 (exp2 domain)
    if (!__all(pmax - mrun <= 8.0f)){
      float mnew = fmaxf(mrun, pmax);
      float sc = __builtin_amdgcn_exp2f(mrun - mnew);
      lrun *= sc;
      #pragma unroll
      for (int r=0;r<16;r++){ o0[r] *= sc; o1[r] *= sc; }
      mrun = mnew;
    }

    #pragma unroll
    for (int r=0;r<16;r++) s[r] = __builtin_amdgcn_exp2f(s[r] - mrun);

    float c0 = (s[0]+s[1])+(s[2]+s[3]), c1 = (s[4]+s[5])+(s[6]+s[7]);
    float c2 = (s[8]+s[9])+(s[10]+s[11]), c3 = (s[12]+s[13])+(s[14]+s[15]);
    float vsum = (c0+c1)+(c2+c3);
    lrun += vsum + sx32f(vsum);

    // ---- P -> per-wave LDS: row q=l31, keys from C/D layout, pairs packed b32
    #pragma unroll
    for (int r=0;r<16;r+=2){
      int key = (r&3) + 8*(r>>2) + 4*hi;         // consecutive pair (key, key+1)
      int w = cvtpk(s[r], s[r+1]);
      *(int*)(pw + l31*64 + ((key*2) ^ swz)) = w;
    }
    asm volatile("s_waitcnt lgkmcnt(0)" ::: "memory");
    __builtin_amdgcn_sched_barrier(0);

    // ---- P^T B-fragments: contiguous 16B reads (elem (hi,j) = key ks*16+hi*8+j)
    bf16x8 pf0 = *(const bf16x8*)(pw + l31*64 + ((hi*16)      ^ swz));
    bf16x8 pf1 = *(const bf16x8*)(pw + l31*64 + ((32 + hi*16) ^ swz));

    // ---- O^T += V^T * P^T
    o0 = __builtin_amdgcn_mfma_f32_32x32x16_bf16(vf0[0], pf0, o0, 0,0,0);
    o0 = __builtin_amdgcn_mfma_f32_32x32x16_bf16(vf0[1], pf1, o0, 0,0,0);
    o1 = __builtin_amdgcn_mfma_f32_32x32x16_bf16(vf1[0], pf0, o1, 0,0,0);
    o1 = __builtin_amdgcn_mfma_f32_32x32x16_bf16(vf1[1], pf1, o1, 0,0,0);

    #pragma unroll
    for (int ks=0;ks<4;ks++) kf[ks] = kn[ks];
  }

  // ---- epilogue: O^T / l -> Aout [B,T,C] bf16 (8B stores)
  float rl = __builtin_amdgcn_rcpf(lrun);
  const int b = bh >> 4, h = bh & 15;
  USHORT* orow = Aout + ((size_t)(b*2048 + qbase + l31))*1024 + h*64;
  #pragma unroll
  for (int g4=0; g4<4; g4++){
    i32x2 u0, u1;
    u0[0] = cvtpk(o0[4*g4]*rl,   o0[4*g4+1]*rl);
    u0[1] = cvtpk(o0[4*g4+2]*rl, o0[4*g4+3]*rl);
    *(i32x2*)(orow + 8*g4 + 4*hi) = u0;
    u1[0] = cvtpk(o1[4*g4]*rl,   o1[4*g4+1]*rl);
    u1[1] = cvtpk(o1[4*g4+2]*rl, o1[4*g4+3]*rl);
    *(i32x2*)(orow + 32 + 8*g4 + 4*hi) = u1;
  }
}

// ---------------- launch ----------------
extern "C" void kernel_launch(void* const* d_in, const int* in_sizes, int n_in,
                              void* d_out, int out_size, void* d_ws, size_t ws_size,
                              hipStream_t stream) {
  const float* x     = (const float*)d_in[0];
  const float* w_qkv = (const float*)d_in[1];
  const float* w_out = (const float*)d_in[2];
  float* out = (float*)d_out;
  char* ws = (char*)d_ws;

  USHORT* xb    = (USHORT*)(ws);               // 16,777,216 B  (reused as VT)
  USHORT* wqkvT = (USHORT*)(ws + 16777216);    //  6,291,456 B
  USHORT* woutT = (USHORT*)(ws + 23068672);    //  2,097,152 B
  USHORT* Qb    = (USHORT*)(ws + 25165824);    // 16,777,216 B
  USHORT* Kb    = (USHORT*)(ws + 41943040);    // 16,777,216 B
  USHORT* Vb    = (USHORT*)(ws + 58720256);    // 16,777,216 B (reused as Aout)
  USHORT* VT    = xb;     // x dead after GEMM1
  USHORT* Aout  = Vb;     // V dead after transpose_v

  cvt_x<<<4096, 256, 0, stream>>>(x, xb);
  transpose_f32_bf16<<<dim3(96,32), dim3(32,8), 0, stream>>>(w_qkv, wqkvT, 1024, 3072);
  transpose_f32_bf16<<<dim3(32,32), dim3(32,8), 0, stream>>>(w_out, woutT, 1024, 1024);
  gemm_bt<1><<<dim3(24,64), 256, 0, stream>>>(xb, wqkvT, nullptr, Qb, Kb, Vb, 8192, 3072, 1024);
  transpose_v<<<dim3(2,64,64), dim3(32,8), 0, stream>>>(Vb, VT);
  attn_kern<<<dim3(16,64), 256, 0, stream>>>(Qb, Kb, VT, Aout);
  gemm_bt<0><<<dim3(8,64), 256, 0, stream>>>(Aout, woutT, out, nullptr, nullptr, nullptr, 8192, 1024, 1024);
}